// Round 14
// baseline (1520.815 us; speedup 1.0000x reference)
//
#include <hip/hip_runtime.h>
#include <stdint.h>

#define NN   50000
#define NE   1600000
#define DIN  128
#define DMID 256
#define DOUT 128
#define NMID 8
#define MAXD 2048                 // degree clamp for capacity bounds
#define NBIN 128                  // degree bins (true max deg ~75, clamp safe)
#define NBKB 196                  // hist/psort node-partition blocks = ceil(NN/256)
#define NG16 3128                 // 16-node groups (3125 real + 3 pad), %4==0
#define NNP  (NG16 * 16)          // 50048: perm padded with sentinel NN
#define ECAP (NE + 64 * MAXD + 256 * NG16)

#define AS1 __attribute__((address_space(1)))
#define AS3 __attribute__((address_space(3)))

typedef unsigned short u16;
typedef unsigned int   u32;
typedef __attribute__((ext_vector_type(8))) short short8;
typedef __attribute__((ext_vector_type(4))) float f32x4;
typedef __attribute__((ext_vector_type(2))) float f32x2;
typedef __attribute__((ext_vector_type(4))) int i32x4;

__device__ __forceinline__ float bf2f(u32 u) {
    union { u32 i; float f; } c; c.i = u << 16; return c.f;
}
__device__ __forceinline__ float ubf_lo(u32 v) {
    union { u32 i; float f; } c; c.i = v << 16; return c.f;
}
__device__ __forceinline__ float ubf_hi(u32 v) {
    union { u32 i; float f; } c; c.i = v & 0xffff0000u; return c.f;
}
__device__ __forceinline__ u16 f2bf(float f) {
    union { float f; u32 i; } c; c.f = f;
    u32 u = c.i;
    return (u16)((u + 0x7fffu + ((u >> 16) & 1u)) >> 16);
}
__device__ __forceinline__ void split2(float v, u16& hi, u16& lo) {
    hi = f2bf(v);
    float r = v - bf2f(hi);
    lo = f2bf(r);
}

// ---------------- preprocessing ----------------
// pass 1: per-edge rank within its dst bucket; counts[] = true degree after.
__global__ void rank_kernel(const int* __restrict__ ei, int* __restrict__ counts,
                            int* __restrict__ rank) {
    int i = (blockIdx.x * blockDim.x + threadIdx.x) * 4;
    if (i < NE) {
        i32x4 d = *(const i32x4*)(ei + NE + i);
        i32x4 r;
        r.x = atomicAdd(&counts[d.x], 1);
        r.y = atomicAdd(&counts[d.y], 1);
        r.z = atomicAdd(&counts[d.z], 1);
        r.w = atomicAdd(&counts[d.w], 1);
        *(i32x4*)(rank + i) = r;
    }
}

// -------- two-level counting sort (no global atomics; r5->r6 win) --------

__global__ __launch_bounds__(256) void hist2_kernel(const int* __restrict__ counts,
                                                    int* __restrict__ bcnt) {
    __shared__ int h[NBIN];
    const int t = threadIdx.x;
    if (t < NBIN) h[t] = 0;
    __syncthreads();
    int i = blockIdx.x * 256 + t;
    if (i < NN) {
        int d = counts[i];
        atomicAdd(&h[d < NBIN ? d : NBIN - 1], 1);
    }
    __syncthreads();
    if (t < NBIN) bcnt[blockIdx.x * NBIN + t] = h[t];
}

__global__ __launch_bounds__(128) void bscan_kernel(const int* __restrict__ bcnt,
                                                    int* __restrict__ bbase) {
    __shared__ int B[NBIN];
    const int b = threadIdx.x;      // one thread per bin
    int run = 0;
    for (int k = 0; k < NBKB; ++k) {
        bbase[k * NBIN + b] = run;  // within-bin prefix across blocks
        run += bcnt[k * NBIN + b];
    }
    __shared__ int S[NBIN];
    S[b] = run;
    __syncthreads();
    if (b == 0) {
        int acc = 0;
        for (int x = NBIN - 1; x >= 0; --x) { B[x] = acc; acc += S[x]; }
    }
    __syncthreads();
    const int add = B[b];
    for (int k = 0; k < NBKB; ++k) bbase[k * NBIN + b] += add;
}

__global__ __launch_bounds__(256) void psort2_kernel(const int* __restrict__ counts,
                                                     const int* __restrict__ bbase,
                                                     int* __restrict__ perm,
                                                     int* __restrict__ posv,
                                                     int* __restrict__ degp,
                                                     float* __restrict__ dinv) {
    __shared__ int h[NBIN];
    const int t = threadIdx.x;
    if (t < NBIN) h[t] = 0;
    __syncthreads();
    int i = blockIdx.x * 256 + t;
    int d = 0, b = 0, r = 0;
    if (i < NN) {
        d = counts[i];
        b = d < NBIN ? d : NBIN - 1;
        r = atomicAdd(&h[b], 1);
    }
    __syncthreads();
    if (i < NN) {
        int pos = bbase[blockIdx.x * NBIN + b] + r;
        perm[pos] = i;
        posv[i] = pos;
        degp[pos] = d;
        dinv[i] = rsqrtf((float)d + 1.0f);
    }
}

// pad perm tail with sentinel node NN (zero row in gs), degree 0.
__global__ void ptail_kernel(int* __restrict__ perm, int* __restrict__ degp) {
    int i = NN + threadIdx.x;
    if (i < NNP) { perm[i] = NN; degp[i] = 0; }
}

// per-group (16 nodes) max degree, padded to multiple of 8 (min 8).
__global__ void gcap_kernel(const int* __restrict__ degp, int* __restrict__ gcap) {
    int g = blockIdx.x * blockDim.x + threadIdx.x;
    if (g < NG16) {
        int m = 0;
        for (int j = 0; j < 16; ++j) {
            int d = degp[g * 16 + j];
            m = d > m ? d : m;
        }
        m = (m + 7) & ~7;
        if (m < 8) m = 8;
        gcap[g] = m;
    }
}

// exclusive prefix of gcap*16 -> gbase (u16-slot units)
__global__ __launch_bounds__(1024) void gscan_kernel(const int* __restrict__ gcap,
                                                     int* __restrict__ gbase) {
    __shared__ int sh[1024];
    const int t = threadIdx.x;
    int loc[4];
    int s = 0;
#pragma unroll
    for (int j = 0; j < 4; ++j) {
        int idx = t * 4 + j;
        int v = (idx < NG16) ? gcap[idx] * 16 : 0;
        loc[j] = s;
        s += v;
    }
    sh[t] = s;
    __syncthreads();
    for (int offs = 1; offs < 1024; offs <<= 1) {
        int x = (t >= offs) ? sh[t - offs] : 0;
        __syncthreads();
        sh[t] += x;
        __syncthreads();
    }
    int base = (t == 0) ? 0 : sh[t - 1];
#pragma unroll
    for (int j = 0; j < 4; ++j) {
        int idx = t * 4 + j;
        if (idx < NG16) gbase[idx] = base + loc[j];
    }
}

// prefill esrc with sentinel node NN (zero gs row) so unpadded slots are benign.
__global__ void efill_kernel(u16* __restrict__ esrc) {
    int i = (blockIdx.x * blockDim.x + threadIdx.x) * 8;
    if (i < ECAP) {
        const int v = NN | (NN << 16);
        *(i32x4*)(esrc + i) = (i32x4){v, v, v, v};
    }
}

// pass 2: scatter src ids into group-transposed slots: esrc[gbase[g] + r*16 + slot].
__global__ void escat_kernel(const int* __restrict__ ei, const int* __restrict__ rank,
                             const int* __restrict__ posv, const int* __restrict__ gbase,
                             u16* __restrict__ esrc) {
    int i = (blockIdx.x * blockDim.x + threadIdx.x) * 4;
    if (i < NE) {
        i32x4 d = *(const i32x4*)(ei + NE + i);
        i32x4 s = *(const i32x4*)(ei + i);
        i32x4 r = *(const i32x4*)(rank + i);
        { int p = posv[d.x]; esrc[gbase[p >> 4] + r.x * 16 + (p & 15)] = (u16)s.x; }
        { int p = posv[d.y]; esrc[gbase[p >> 4] + r.y * 16 + (p & 15)] = (u16)s.y; }
        { int p = posv[d.z]; esrc[gbase[p >> 4] + r.z * 16 + (p & 15)] = (u16)s.z; }
        { int p = posv[d.w]; esrc[gbase[p >> 4] + r.w * 16 + (p & 15)] = (u16)s.w; }
    }
}

// zero the sentinel row (node NN) of each of the 8 slices of gs.
__global__ void zsent_kernel(u16* __restrict__ gs) {
    int s = threadIdx.x >> 5, c = threadIdx.x & 31;
    gs[((size_t)s * (NN + 1) + NN) * 32 + c] = 0;
}

// W [K x Dc] fp32 row-major -> slice-major bf16 split: Whi[((k/32)*Dc + d)*32 + k%32]
__global__ void wsplit_kernel(const float* __restrict__ W, u16* __restrict__ Whi,
                              u16* __restrict__ Wlo, int K, int Dc) {
    int idx = blockIdx.x * blockDim.x + threadIdx.x;
    if (idx < K * Dc) {
        int k = idx / Dc, d = idx - k * Dc;
        u16 hi, lo;
        split2(W[idx], hi, lo);
        size_t o = ((size_t)(k >> 5) * Dc + d) * 32 + (k & 31);
        Whi[o] = hi;
        Wlo[o] = lo;
    }
}

// x [NN][128] fp32 -> row-major bf16 hi/lo
__global__ void xsplit_kernel(const float* __restrict__ x, u16* __restrict__ xhi,
                              u16* __restrict__ xlo) {
    int i = blockIdx.x * blockDim.x + threadIdx.x;
    int stride = gridDim.x * blockDim.x;
    for (; i < NN * DIN; i += stride) {
        u16 hi, lo;
        split2(x[i], hi, lo);
        xhi[i] = hi;
        xlo[i] = lo;
    }
}

// ---------------- GEMM v10: 256-row tile (halved W restaging) ---------------
// r13 showed gemm is TRAFFIC-bound (BK=64 barrier-halving was null). W restage
// dominates: 391 blocks x 256 KB = 100 MB/layer. This version: 1024-thread
// blocks (16 waves), each block = 256 rows x Dc cols; wave = 16 rows x Dc.
// Grid 196 -> W restage 50 MB/layer; A read once (51 MB); C 25 MB.
// acc = (Dc/16) f32x4 = 64 regs (Dc=256) + frags ~ 100 total < 128 cap.
template <int K, int Dc>
__global__ __launch_bounds__(1024, 4) void gemm_kernel(const u16* __restrict__ xhi,
                                                       const u16* __restrict__ xlo,
                                                       const u16* __restrict__ whi,
                                                       const u16* __restrict__ wlo,
                                                       const float* __restrict__ dinv,
                                                       u16* __restrict__ gs) {
    constexpr int NTW = Dc / 16;          // col-tiles per wave (16 for 256)
    constexpr int KS = K / 32;
    __shared__ u16 bh[Dc * 32];
    __shared__ u16 bl[Dc * 32];
    const int tid = threadIdx.x;
    const int wid = tid >> 6;             // 0..15 row panel (16 rows each)
    const int lane = tid & 63;
    const int m = lane & 15, quad = lane >> 4;
    const int rowBase = blockIdx.x * 256 + wid * 16;

    f32x4 acc[NTW];
#pragma unroll
    for (int t = 0; t < NTW; ++t) acc[t] = (f32x4){0.f, 0.f, 0.f, 0.f};

    int rowA = rowBase + m;
    if (rowA > NN - 1) rowA = NN - 1;
    const size_t arow = (size_t)rowA * K + quad * 8;

    for (int ks = 0; ks < KS; ++ks) {
        const u16* sh_src = whi + (size_t)ks * Dc * 32;
        const u16* sl_src = wlo + (size_t)ks * Dc * 32;
        __syncthreads();
        {   // stage Dc*32 u16 per array; Dc*4 16B-units; 1024 threads
            int j = tid;
            if (j < Dc * 4) {
                __builtin_amdgcn_global_load_lds((const AS1 void*)(sh_src + j * 8),
                                                 (AS3 void*)((AS3 u16*)bh + j * 8), 16, 0, 0);
                __builtin_amdgcn_global_load_lds((const AS1 void*)(sl_src + j * 8),
                                                 (AS3 void*)((AS3 u16*)bl + j * 8), 16, 0, 0);
            }
        }
        short8 ah = *(const short8*)(xhi + arow + ks * 32);
        short8 al = *(const short8*)(xlo + arow + ks * 32);
        __syncthreads();
#pragma unroll
        for (int t = 0; t < NTW; ++t) {
            const int bo = (t * 16 + m) * 32 + quad * 8;
            short8 wh = *(const short8*)(bh + bo);
            short8 wl = *(const short8*)(bl + bo);
            acc[t] = __builtin_amdgcn_mfma_f32_16x16x32_bf16(ah, wh, acc[t], 0, 0, 0);
            acc[t] = __builtin_amdgcn_mfma_f32_16x16x32_bf16(al, wh, acc[t], 0, 0, 0);
            acc[t] = __builtin_amdgcn_mfma_f32_16x16x32_bf16(ah, wl, acc[t], 0, 0, 0);
        }
    }

    const int r0 = rowBase + quad * 4;
    float dv[4];
#pragma unroll
    for (int r = 0; r < 4; ++r) {
        int rr = r0 + r;
        dv[r] = (rr < NN) ? dinv[rr] : 0.f;
    }
#pragma unroll
    for (int t = 0; t < NTW; ++t) {
        const int col = t * 16 + m;
#pragma unroll
        for (int r = 0; r < 4; ++r) {
            int rr = r0 + r;
            if (rr < NN) {
                size_t o = ((size_t)(col >> 5) * (NN + 1) + rr) * 32 + (col & 31);
                gs[o] = f2bf(acc[t][r] * dv[r]);
            }
        }
    }
}

// ---------------- sliced aggregation (r9 verbatim: 77 us floor) -------------
#define CONSROW(X) do { \
    a[0] += ubf_lo((X).x); a[1] += ubf_hi((X).x); \
    a[2] += ubf_lo((X).y); a[3] += ubf_hi((X).y); \
    a[4] += ubf_lo((X).z); a[5] += ubf_hi((X).z); \
    a[6] += ubf_lo((X).w); a[7] += ubf_hi((X).w); } while (0)

template <int Dc, bool FINAL>
__global__ __launch_bounds__(256, 4) void agg_kernel(const u16* __restrict__ gs,
                                                     const u16* __restrict__ esrc,
                                                     const int* __restrict__ gbase,
                                                     const int* __restrict__ gcap,
                                                     const int* __restrict__ perm,
                                                     const float* __restrict__ dinv,
                                                     const float* __restrict__ bias,
                                                     float* __restrict__ vs,
                                                     float* __restrict__ part,
                                                     float* __restrict__ outf) {
    constexpr int NSL = Dc / 32;
    constexpr int SH = (NSL == 8) ? 3 : 2;
    const int slice = blockIdx.x & (NSL - 1);
    const int grp4 = blockIdx.x >> SH;
    const int wid = threadIdx.x >> 6, lane = threadIdx.x & 63;
    const int grp = grp4 * 4 + wid;          // 16-node group id (wave-uniform)
    const int nslot = lane >> 2, q = lane & 3;
    const int gpos = grp * 16 + nslot;       // perm index
    const int node = perm[gpos];             // NN for padding lanes
    const int nt = gcap[grp];                // uniform trip count, mult of 8, >=8

    const u16* gslb = gs + (size_t)slice * (NN + 1) * 32 + q * 8;  // quarter base
    const u16* ep = esrc + gbase[grp] + nslot;

    float a[8];
#pragma unroll
    for (int j = 0; j < 8; ++j) a[j] = 0.f;

    // ---- prologue: srcs chunks 0,1; self row; rows chunks 0,1; srcs 2,3 ----
    int a0 = (int)ep[0],   a1 = (int)ep[16],  a2 = (int)ep[32],  a3 = (int)ep[48];
    int b0 = (int)ep[64],  b1 = (int)ep[80],  b2 = (int)ep[96],  b3 = (int)ep[112];
    uint4 RS = *(const uint4*)(gslb + (size_t)node * 32);
    uint4 A0 = *(const uint4*)(gslb + (size_t)a0 * 32);
    uint4 A1 = *(const uint4*)(gslb + (size_t)a1 * 32);
    uint4 A2 = *(const uint4*)(gslb + (size_t)a2 * 32);
    uint4 A3 = *(const uint4*)(gslb + (size_t)a3 * 32);
    uint4 B0 = *(const uint4*)(gslb + (size_t)b0 * 32);
    uint4 B1 = *(const uint4*)(gslb + (size_t)b1 * 32);
    uint4 B2 = *(const uint4*)(gslb + (size_t)b2 * 32);
    uint4 B3 = *(const uint4*)(gslb + (size_t)b3 * 32);
    CONSROW(RS);
    if (8 < nt) {   // srcs chunk 2 (slots 8..11)
        a0 = (int)ep[128]; a1 = (int)ep[144]; a2 = (int)ep[160]; a3 = (int)ep[176];
    }
    if (12 < nt) {  // srcs chunk 3 (slots 12..15)
        b0 = (int)ep[192]; b1 = (int)ep[208]; b2 = (int)ep[224]; b3 = (int)ep[240];
    }

    // ---- main loop: 2 chunks (8 rows) per iteration ----
    int c = 0;  // chunk index (4 slots each); nt/4 chunks total, even
    for (;;) {
        CONSROW(A0); CONSROW(A1); CONSROW(A2); CONSROW(A3);        // chunk c
        if ((c + 2) * 4 >= nt) {
            CONSROW(B0); CONSROW(B1); CONSROW(B2); CONSROW(B3);    // chunk c+1
            break;
        }
        A0 = *(const uint4*)(gslb + (size_t)a0 * 32);              // rows chunk c+2
        A1 = *(const uint4*)(gslb + (size_t)a1 * 32);
        A2 = *(const uint4*)(gslb + (size_t)a2 * 32);
        A3 = *(const uint4*)(gslb + (size_t)a3 * 32);
        if ((c + 4) * 4 < nt) {                                    // srcs chunk c+4
            const u16* sp = ep + (size_t)(c + 4) * 64;
            a0 = (int)sp[0]; a1 = (int)sp[16]; a2 = (int)sp[32]; a3 = (int)sp[48];
        }
        CONSROW(B0); CONSROW(B1); CONSROW(B2); CONSROW(B3);        // chunk c+1
        B0 = *(const uint4*)(gslb + (size_t)b0 * 32);              // rows chunk c+3
        B1 = *(const uint4*)(gslb + (size_t)b1 * 32);
        B2 = *(const uint4*)(gslb + (size_t)b2 * 32);
        B3 = *(const uint4*)(gslb + (size_t)b3 * 32);
        if ((c + 5) * 4 < nt) {                                    // srcs chunk c+5
            const u16* sp = ep + (size_t)(c + 5) * 64;
            b0 = (int)sp[0]; b1 = (int)sp[16]; b2 = (int)sp[32]; b3 = (int)sp[48];
        }
        c += 2;
    }

    if (node < NN) {
        const float dv = dinv[node];
        const int f = slice * 32 + q * 8;
        float v[8];
        f32x4 bb0 = *(const f32x4*)(bias + f);
        f32x4 bb1 = *(const f32x4*)(bias + f + 4);
#pragma unroll
        for (int j = 0; j < 4; ++j) v[j] = a[j] * dv + bb0[j];
#pragma unroll
        for (int j = 0; j < 4; ++j) v[j + 4] = a[j + 4] * dv + bb1[j];

        if (FINAL) {
            float* op = outf + (size_t)node * Dc + f;
            *(f32x4*)op = (f32x4){v[0], v[1], v[2], v[3]};
            *(f32x4*)(op + 4) = (f32x4){v[4], v[5], v[6], v[7]};
        } else {
            float* vp = vs + ((size_t)slice * NN + node) * 32 + q * 8;
            *(f32x4*)vp = (f32x4){v[0], v[1], v[2], v[3]};
            *(f32x4*)(vp + 4) = (f32x4){v[4], v[5], v[6], v[7]};
            float p1 = 0.f, p2 = 0.f;
#pragma unroll
            for (int j = 0; j < 8; ++j) {
                p1 += v[j];
                p2 += v[j] * v[j];
            }
            // quad reduction (4 lanes of this node)
            p1 += __shfl_xor(p1, 1, 64); p2 += __shfl_xor(p2, 1, 64);
            p1 += __shfl_xor(p1, 2, 64); p2 += __shfl_xor(p2, 2, 64);
            // part[slice][node]: per-XCD-contiguous -> no cross-XCD false sharing
            if (q == 0)
                *(f32x2*)(part + ((size_t)slice * NN + node) * 2) = (f32x2){p1, p2};
        }
    }
}

// ---------------- LN + SiLU + bf16 hi/lo split (streaming, r9 verbatim) ------
__global__ __launch_bounds__(256) void ln_kernel(const float* __restrict__ vs,
                                                 const float* __restrict__ part,
                                                 const float* __restrict__ gamma,
                                                 const float* __restrict__ beta,
                                                 u16* __restrict__ xhi,
                                                 u16* __restrict__ xlo) {
    const int wid = threadIdx.x >> 6, lane = threadIdx.x & 63;
    const int node = blockIdx.x * 4 + wid;
    const int s = lane >> 3, o = (lane & 7) * 4;

    f32x4 vv = *(const f32x4*)(vs + ((size_t)s * NN + node) * 32 + o);
    f32x2 p = *(const f32x2*)(part + ((size_t)(lane & 7) * NN + node) * 2);
    float s1 = p.x, s2 = p.y;
    s1 += __shfl_xor(s1, 1, 64); s2 += __shfl_xor(s2, 1, 64);
    s1 += __shfl_xor(s1, 2, 64); s2 += __shfl_xor(s2, 2, 64);
    s1 += __shfl_xor(s1, 4, 64); s2 += __shfl_xor(s2, 4, 64);

    const float mu = s1 * (1.f / 256.f);
    const float var = s2 * (1.f / 256.f) - mu * mu;
    const float rstd = rsqrtf(fmaxf(var, 0.f) + 1e-5f);

    const int f = s * 32 + o;
    u16 hh[4], ll[4];
#pragma unroll
    for (int j = 0; j < 4; ++j) {
        float y = (vv[j] - mu) * rstd * gamma[f + j] + beta[f + j];
        y = y / (1.f + __expf(-y));
        split2(y, hh[j], ll[j]);
    }
    uint2 oh, ol;
    oh.x = (u32)hh[0] | ((u32)hh[1] << 16);
    oh.y = (u32)hh[2] | ((u32)hh[3] << 16);
    ol.x = (u32)ll[0] | ((u32)ll[1] << 16);
    ol.y = (u32)ll[2] | ((u32)ll[3] << 16);
    *(uint2*)(xhi + (size_t)node * 256 + f) = oh;
    *(uint2*)(xlo + (size_t)node * 256 + f) = ol;
}

// ---------------- launcher ----------------

extern "C" void kernel_launch(void* const* d_in, const int* in_sizes, int n_in,
                              void* d_out, int out_size, void* d_ws, size_t ws_size,
                              hipStream_t stream) {
    (void)in_sizes; (void)n_in; (void)out_size; (void)ws_size;
    const float* x_in  = (const float*)d_in[0];
    const int*   ei    = (const int*)d_in[1];
    const float* W_in  = (const float*)d_in[2];
    const float* b_in  = (const float*)d_in[3];
    const float* W_mid = (const float*)d_in[4];
    const float* b_mid = (const float*)d_in[5];
    const float* W_out = (const float*)d_in[6];
    const float* b_out = (const float*)d_in[7];
    const float* gamma = (const float*)d_in[8];
    const float* beta  = (const float*)d_in[9];

    char* ws = (char*)d_ws;
    size_t off = 0;
    auto alloc = [&](size_t bytes) -> char* {
        char* p = ws + off;
        off += (bytes + 255) & ~(size_t)255;
        return p;
    };
    float* dinv   = (float*)alloc((size_t)NN * 4);
    int* counts   = (int*)alloc((size_t)NN * 4);
    int* rank     = (int*)alloc((size_t)NE * 4);
    int* bcnt     = (int*)alloc((size_t)NBKB * NBIN * 4);
    int* bbase    = (int*)alloc((size_t)NBKB * NBIN * 4);
    int* perm     = (int*)alloc((size_t)NNP * 4);
    int* posv     = (int*)alloc((size_t)NN * 4);
    int* degp     = (int*)alloc((size_t)NNP * 4);
    int* gcap     = (int*)alloc((size_t)NG16 * 4);
    int* gbase    = (int*)alloc((size_t)NG16 * 4);
    u16* esrc     = (u16*)alloc((size_t)ECAP * 2);
    u16* whi_in   = (u16*)alloc((size_t)DIN * DMID * 2);
    u16* wlo_in   = (u16*)alloc((size_t)DIN * DMID * 2);
    u16* whi_mid  = (u16*)alloc((size_t)NMID * DMID * DMID * 2);
    u16* wlo_mid  = (u16*)alloc((size_t)NMID * DMID * DMID * 2);
    u16* whi_out  = (u16*)alloc((size_t)DMID * DOUT * 2);
    u16* wlo_out  = (u16*)alloc((size_t)DMID * DOUT * 2);
    u16* xhi      = (u16*)alloc((size_t)NN * DMID * 2);
    u16* xlo      = (u16*)alloc((size_t)NN * DMID * 2);
    u16* gs       = (u16*)alloc((size_t)8 * (NN + 1) * 32 * 2);  // sliced g
    float* vs     = (float*)alloc((size_t)NN * DMID * 4);        // pre-LN v, sliced
    float* part   = (float*)alloc((size_t)8 * NN * 2 * 4);       // [slice][node]{2}

    hipMemsetAsync(counts, 0, (size_t)NN * 4, stream);

    const int EB4 = (NE / 4 + 255) / 256;       // 1563
    rank_kernel<<<EB4, 256, 0, stream>>>(ei, counts, rank);
    hist2_kernel<<<NBKB, 256, 0, stream>>>(counts, bcnt);
    bscan_kernel<<<1, 128, 0, stream>>>(bcnt, bbase);
    psort2_kernel<<<NBKB, 256, 0, stream>>>(counts, bbase, perm, posv, degp, dinv);
    ptail_kernel<<<1, 64, 0, stream>>>(perm, degp);
    gcap_kernel<<<(NG16 + 255) / 256, 256, 0, stream>>>(degp, gcap);
    gscan_kernel<<<1, 1024, 0, stream>>>(gcap, gbase);
    efill_kernel<<<(ECAP / 8 + 255) / 256, 256, 0, stream>>>(esrc);
    escat_kernel<<<EB4, 256, 0, stream>>>(ei, rank, posv, gbase, esrc);
    zsent_kernel<<<1, 256, 0, stream>>>(gs);

    wsplit_kernel<<<(DIN * DMID + 255) / 256, 256, 0, stream>>>(W_in, whi_in, wlo_in, DIN, DMID);
    for (int i = 0; i < NMID; ++i)
        wsplit_kernel<<<(DMID * DMID + 255) / 256, 256, 0, stream>>>(
            W_mid + (size_t)i * DMID * DMID, whi_mid + (size_t)i * DMID * DMID,
            wlo_mid + (size_t)i * DMID * DMID, DMID, DMID);
    wsplit_kernel<<<(DMID * DOUT + 255) / 256, 256, 0, stream>>>(W_out, whi_out, wlo_out, DMID, DOUT);
    xsplit_kernel<<<1024, 256, 0, stream>>>(x_in, xhi, xlo);

    const int GB = (NN + 255) / 256;            // 196 (16 waves/block, 256 rows)
    const int AGM = (NG16 / 4) * 8;             // 6256: 8 slices x 782 group-quads
    const int AGF = (NG16 / 4) * 4;             // 3128: 4 slices
    const int LNB = NN / 4;                     // 12500

    // layer 0: 128 -> 256
    gemm_kernel<DIN, DMID><<<GB, 1024, 0, stream>>>(xhi, xlo, whi_in, wlo_in, dinv, gs);
    agg_kernel<DMID, false><<<AGM, 256, 0, stream>>>(gs, esrc, gbase, gcap, perm,
                                                     dinv, b_in, vs, part, nullptr);
    ln_kernel<<<LNB, 256, 0, stream>>>(vs, part, gamma, beta, xhi, xlo);
    // 8 mid layers: 256 -> 256
    for (int i = 0; i < NMID; ++i) {
        gemm_kernel<DMID, DMID><<<GB, 1024, 0, stream>>>(xhi, xlo,
                                                         whi_mid + (size_t)i * DMID * DMID,
                                                         wlo_mid + (size_t)i * DMID * DMID,
                                                         dinv, gs);
        agg_kernel<DMID, false><<<AGM, 256, 0, stream>>>(gs, esrc, gbase, gcap, perm,
                                                         dinv, b_mid + (size_t)i * DMID,
                                                         vs, part, nullptr);
        ln_kernel<<<LNB, 256, 0, stream>>>(vs, part,
                                           gamma + (size_t)(i + 1) * DMID,
                                           beta + (size_t)(i + 1) * DMID, xhi, xlo);
    }
    // final layer: 256 -> 128, no LN/SiLU; agg writes fp32 out directly
    gemm_kernel<DMID, DOUT><<<GB, 1024, 0, stream>>>(xhi, xlo, whi_out, wlo_out, dinv, gs);
    agg_kernel<DOUT, true><<<AGF, 256, 0, stream>>>(gs, esrc, gbase, gcap, perm,
                                                    dinv, b_out, nullptr, nullptr,
                                                    (float*)d_out);
}

// Round 15
// 1419.555 us; speedup vs baseline: 1.0713x; 1.0713x over previous
//
#include <hip/hip_runtime.h>
#include <stdint.h>

#define NN   50000
#define NE   1600000
#define DIN  128
#define DMID 256
#define DOUT 128
#define NMID 8
#define MAXD 2048                 // degree clamp for capacity bounds
#define NBIN 128                  // degree bins (true max deg ~75, clamp safe)
#define NBKB 196                  // hist/psort node-partition blocks = ceil(NN/256)
#define NG16 3128                 // 16-node groups (3125 real + 3 pad), %4==0
#define NNP  (NG16 * 16)          // 50048: perm padded with sentinel NN
#define ECAP (NE + 64 * MAXD + 256 * NG16)

#define AS1 __attribute__((address_space(1)))
#define AS3 __attribute__((address_space(3)))

typedef unsigned short u16;
typedef unsigned int   u32;
typedef __attribute__((ext_vector_type(8))) short short8;
typedef __attribute__((ext_vector_type(4))) float f32x4;
typedef __attribute__((ext_vector_type(2))) float f32x2;
typedef __attribute__((ext_vector_type(4))) int i32x4;

__device__ __forceinline__ float bf2f(u32 u) {
    union { u32 i; float f; } c; c.i = u << 16; return c.f;
}
__device__ __forceinline__ float ubf_lo(u32 v) {
    union { u32 i; float f; } c; c.i = v << 16; return c.f;
}
__device__ __forceinline__ float ubf_hi(u32 v) {
    union { u32 i; float f; } c; c.i = v & 0xffff0000u; return c.f;
}
__device__ __forceinline__ u16 f2bf(float f) {
    union { float f; u32 i; } c; c.f = f;
    u32 u = c.i;
    return (u16)((u + 0x7fffu + ((u >> 16) & 1u)) >> 16);
}
__device__ __forceinline__ void split2(float v, u16& hi, u16& lo) {
    hi = f2bf(v);
    float r = v - bf2f(hi);
    lo = f2bf(r);
}

// ---------------- preprocessing ----------------
// pass 1: per-edge rank within its dst bucket; counts[] = true degree after.
__global__ void rank_kernel(const int* __restrict__ ei, int* __restrict__ counts,
                            int* __restrict__ rank) {
    int i = (blockIdx.x * blockDim.x + threadIdx.x) * 4;
    if (i < NE) {
        i32x4 d = *(const i32x4*)(ei + NE + i);
        i32x4 r;
        r.x = atomicAdd(&counts[d.x], 1);
        r.y = atomicAdd(&counts[d.y], 1);
        r.z = atomicAdd(&counts[d.z], 1);
        r.w = atomicAdd(&counts[d.w], 1);
        *(i32x4*)(rank + i) = r;
    }
}

// -------- two-level counting sort (no global atomics; r5->r6 win) --------

__global__ __launch_bounds__(256) void hist2_kernel(const int* __restrict__ counts,
                                                    int* __restrict__ bcnt) {
    __shared__ int h[NBIN];
    const int t = threadIdx.x;
    if (t < NBIN) h[t] = 0;
    __syncthreads();
    int i = blockIdx.x * 256 + t;
    if (i < NN) {
        int d = counts[i];
        atomicAdd(&h[d < NBIN ? d : NBIN - 1], 1);
    }
    __syncthreads();
    if (t < NBIN) bcnt[blockIdx.x * NBIN + t] = h[t];
}

__global__ __launch_bounds__(128) void bscan_kernel(const int* __restrict__ bcnt,
                                                    int* __restrict__ bbase) {
    __shared__ int B[NBIN];
    const int b = threadIdx.x;      // one thread per bin
    int run = 0;
    for (int k = 0; k < NBKB; ++k) {
        bbase[k * NBIN + b] = run;  // within-bin prefix across blocks
        run += bcnt[k * NBIN + b];
    }
    __shared__ int S[NBIN];
    S[b] = run;
    __syncthreads();
    if (b == 0) {
        int acc = 0;
        for (int x = NBIN - 1; x >= 0; --x) { B[x] = acc; acc += S[x]; }
    }
    __syncthreads();
    const int add = B[b];
    for (int k = 0; k < NBKB; ++k) bbase[k * NBIN + b] += add;
}

__global__ __launch_bounds__(256) void psort2_kernel(const int* __restrict__ counts,
                                                     const int* __restrict__ bbase,
                                                     int* __restrict__ perm,
                                                     int* __restrict__ posv,
                                                     int* __restrict__ degp,
                                                     float* __restrict__ dinv) {
    __shared__ int h[NBIN];
    const int t = threadIdx.x;
    if (t < NBIN) h[t] = 0;
    __syncthreads();
    int i = blockIdx.x * 256 + t;
    int d = 0, b = 0, r = 0;
    if (i < NN) {
        d = counts[i];
        b = d < NBIN ? d : NBIN - 1;
        r = atomicAdd(&h[b], 1);
    }
    __syncthreads();
    if (i < NN) {
        int pos = bbase[blockIdx.x * NBIN + b] + r;
        perm[pos] = i;
        posv[i] = pos;
        degp[pos] = d;
        dinv[i] = rsqrtf((float)d + 1.0f);
    }
}

// pad perm tail with sentinel node NN (zero row in gs), degree 0.
__global__ void ptail_kernel(int* __restrict__ perm, int* __restrict__ degp) {
    int i = NN + threadIdx.x;
    if (i < NNP) { perm[i] = NN; degp[i] = 0; }
}

// per-group (16 nodes) max degree, padded to multiple of 8 (min 8).
__global__ void gcap_kernel(const int* __restrict__ degp, int* __restrict__ gcap) {
    int g = blockIdx.x * blockDim.x + threadIdx.x;
    if (g < NG16) {
        int m = 0;
        for (int j = 0; j < 16; ++j) {
            int d = degp[g * 16 + j];
            m = d > m ? d : m;
        }
        m = (m + 7) & ~7;
        if (m < 8) m = 8;
        gcap[g] = m;
    }
}

// exclusive prefix of gcap*16 -> gbase (u16-slot units)
__global__ __launch_bounds__(1024) void gscan_kernel(const int* __restrict__ gcap,
                                                     int* __restrict__ gbase) {
    __shared__ int sh[1024];
    const int t = threadIdx.x;
    int loc[4];
    int s = 0;
#pragma unroll
    for (int j = 0; j < 4; ++j) {
        int idx = t * 4 + j;
        int v = (idx < NG16) ? gcap[idx] * 16 : 0;
        loc[j] = s;
        s += v;
    }
    sh[t] = s;
    __syncthreads();
    for (int offs = 1; offs < 1024; offs <<= 1) {
        int x = (t >= offs) ? sh[t - offs] : 0;
        __syncthreads();
        sh[t] += x;
        __syncthreads();
    }
    int base = (t == 0) ? 0 : sh[t - 1];
#pragma unroll
    for (int j = 0; j < 4; ++j) {
        int idx = t * 4 + j;
        if (idx < NG16) gbase[idx] = base + loc[j];
    }
}

// prefill esrc with sentinel node NN (zero gs row) so unpadded slots are benign.
__global__ void efill_kernel(u16* __restrict__ esrc) {
    int i = (blockIdx.x * blockDim.x + threadIdx.x) * 8;
    if (i < ECAP) {
        const int v = NN | (NN << 16);
        *(i32x4*)(esrc + i) = (i32x4){v, v, v, v};
    }
}

// pass 2: scatter src ids into group-transposed slots: esrc[gbase[g] + r*16 + slot].
__global__ void escat_kernel(const int* __restrict__ ei, const int* __restrict__ rank,
                             const int* __restrict__ posv, const int* __restrict__ gbase,
                             u16* __restrict__ esrc) {
    int i = (blockIdx.x * blockDim.x + threadIdx.x) * 4;
    if (i < NE) {
        i32x4 d = *(const i32x4*)(ei + NE + i);
        i32x4 s = *(const i32x4*)(ei + i);
        i32x4 r = *(const i32x4*)(rank + i);
        { int p = posv[d.x]; esrc[gbase[p >> 4] + r.x * 16 + (p & 15)] = (u16)s.x; }
        { int p = posv[d.y]; esrc[gbase[p >> 4] + r.y * 16 + (p & 15)] = (u16)s.y; }
        { int p = posv[d.z]; esrc[gbase[p >> 4] + r.z * 16 + (p & 15)] = (u16)s.z; }
        { int p = posv[d.w]; esrc[gbase[p >> 4] + r.w * 16 + (p & 15)] = (u16)s.w; }
    }
}

// zero the sentinel row (node NN) of each of the 8 slices of gs.
__global__ void zsent_kernel(u16* __restrict__ gs) {
    int s = threadIdx.x >> 5, c = threadIdx.x & 31;
    gs[((size_t)s * (NN + 1) + NN) * 32 + c] = 0;
}

// W [K x Dc] fp32 row-major -> slice-major bf16 split: Whi[((k/32)*Dc + d)*32 + k%32]
__global__ void wsplit_kernel(const float* __restrict__ W, u16* __restrict__ Whi,
                              u16* __restrict__ Wlo, int K, int Dc) {
    int idx = blockIdx.x * blockDim.x + threadIdx.x;
    if (idx < K * Dc) {
        int k = idx / Dc, d = idx - k * Dc;
        u16 hi, lo;
        split2(W[idx], hi, lo);
        size_t o = ((size_t)(k >> 5) * Dc + d) * 32 + (k & 31);
        Whi[o] = hi;
        Wlo[o] = lo;
    }
}

// all NMID mid-layer W's in ONE launch (saves 7 dispatch gaps vs per-layer).
__global__ void wsplitall_kernel(const float* __restrict__ W, u16* __restrict__ Whi,
                                 u16* __restrict__ Wlo) {
    int idx = blockIdx.x * blockDim.x + threadIdx.x;
    if (idx < NMID * DMID * DMID) {
        int l = idx / (DMID * DMID);
        int rem = idx - l * (DMID * DMID);
        int k = rem / DMID, d = rem - k * DMID;
        u16 hi, lo;
        split2(W[idx], hi, lo);
        size_t o = (size_t)l * DMID * DMID + ((size_t)(k >> 5) * DMID + d) * 32 + (k & 31);
        Whi[o] = hi;
        Wlo[o] = lo;
    }
}

// x [NN][128] fp32 -> row-major bf16 hi/lo
__global__ void xsplit_kernel(const float* __restrict__ x, u16* __restrict__ xhi,
                              u16* __restrict__ xlo) {
    int i = blockIdx.x * blockDim.x + threadIdx.x;
    int stride = gridDim.x * blockDim.x;
    for (; i < NN * DIN; i += stride) {
        u16 hi, lo;
        split2(x[i], hi, lo);
        xhi[i] = hi;
        xlo[i] = lo;
    }
}

// ---------------- GEMM (r9 verbatim, best measured ~55 us) ------------------
template <int K, int Dc>
__global__ __launch_bounds__(512, 4) void gemm_kernel(const u16* __restrict__ xhi,
                                                      const u16* __restrict__ xlo,
                                                      const u16* __restrict__ whi,
                                                      const u16* __restrict__ wlo,
                                                      const float* __restrict__ dinv,
                                                      u16* __restrict__ gs) {
    constexpr int NTW = Dc / 32;
    constexpr int KS = K / 32;
    __shared__ u16 bh[Dc * 32];
    __shared__ u16 bl[Dc * 32];
    const int tid = threadIdx.x;
    const int wid = tid >> 6;
    const int rowPanel = wid >> 1;
    const int colPanel = wid & 1;
    const int lane = tid & 63;
    const int m = lane & 15, quad = lane >> 4;
    const int rowBase = blockIdx.x * 128 + rowPanel * 32;

    f32x4 acc[2][NTW];
#pragma unroll
    for (int rg = 0; rg < 2; ++rg)
#pragma unroll
        for (int t = 0; t < NTW; ++t) acc[rg][t] = (f32x4){0.f, 0.f, 0.f, 0.f};

    size_t arow[2];
#pragma unroll
    for (int rg = 0; rg < 2; ++rg) {
        int rowA = rowBase + rg * 16 + m;
        if (rowA > NN - 1) rowA = NN - 1;
        arow[rg] = (size_t)rowA * K + quad * 8;
    }

    for (int ks = 0; ks < KS; ++ks) {
        const u16* sh_src = whi + (size_t)ks * Dc * 32;
        const u16* sl_src = wlo + (size_t)ks * Dc * 32;
        __syncthreads();
#pragma unroll
        for (int i = 0; i < Dc * 4; i += 512) {
            int j = i + tid;
            __builtin_amdgcn_global_load_lds((const AS1 void*)(sh_src + j * 8),
                                             (AS3 void*)((AS3 u16*)bh + j * 8), 16, 0, 0);
            __builtin_amdgcn_global_load_lds((const AS1 void*)(sl_src + j * 8),
                                             (AS3 void*)((AS3 u16*)bl + j * 8), 16, 0, 0);
        }
        short8 ah[2], al[2];
#pragma unroll
        for (int rg = 0; rg < 2; ++rg) {
            ah[rg] = *(const short8*)(xhi + arow[rg] + ks * 32);
            al[rg] = *(const short8*)(xlo + arow[rg] + ks * 32);
        }
        __syncthreads();
#pragma unroll
        for (int t = 0; t < NTW; ++t) {
            const int bo = ((colPanel * NTW + t) * 16 + m) * 32 + quad * 8;
            short8 wh = *(const short8*)(bh + bo);
            short8 wl = *(const short8*)(bl + bo);
#pragma unroll
            for (int rg = 0; rg < 2; ++rg) {
                acc[rg][t] = __builtin_amdgcn_mfma_f32_16x16x32_bf16(ah[rg], wh, acc[rg][t], 0, 0, 0);
                acc[rg][t] = __builtin_amdgcn_mfma_f32_16x16x32_bf16(al[rg], wh, acc[rg][t], 0, 0, 0);
                acc[rg][t] = __builtin_amdgcn_mfma_f32_16x16x32_bf16(ah[rg], wl, acc[rg][t], 0, 0, 0);
            }
        }
    }

#pragma unroll
    for (int rg = 0; rg < 2; ++rg) {
        const int r0 = rowBase + rg * 16 + quad * 4;
        float dv[4];
#pragma unroll
        for (int r = 0; r < 4; ++r) {
            int rr = r0 + r;
            dv[r] = (rr < NN) ? dinv[rr] : 0.f;
        }
#pragma unroll
        for (int t = 0; t < NTW; ++t) {
            const int col = colPanel * (Dc / 2) + t * 16 + m;
#pragma unroll
            for (int r = 0; r < 4; ++r) {
                int rr = r0 + r;
                if (rr < NN) {
                    size_t o = ((size_t)(col >> 5) * (NN + 1) + rr) * 32 + (col & 31);
                    gs[o] = f2bf(acc[rg][t][r] * dv[r]);
                }
            }
        }
    }
}

// ---------------- sliced aggregation (r9 verbatim: 77 us floor) -------------
#define CONSROW(X) do { \
    a[0] += ubf_lo((X).x); a[1] += ubf_hi((X).x); \
    a[2] += ubf_lo((X).y); a[3] += ubf_hi((X).y); \
    a[4] += ubf_lo((X).z); a[5] += ubf_hi((X).z); \
    a[6] += ubf_lo((X).w); a[7] += ubf_hi((X).w); } while (0)

template <int Dc, bool FINAL>
__global__ __launch_bounds__(256, 4) void agg_kernel(const u16* __restrict__ gs,
                                                     const u16* __restrict__ esrc,
                                                     const int* __restrict__ gbase,
                                                     const int* __restrict__ gcap,
                                                     const int* __restrict__ perm,
                                                     const float* __restrict__ dinv,
                                                     const float* __restrict__ bias,
                                                     float* __restrict__ vs,
                                                     float* __restrict__ part,
                                                     float* __restrict__ outf) {
    constexpr int NSL = Dc / 32;
    constexpr int SH = (NSL == 8) ? 3 : 2;
    const int slice = blockIdx.x & (NSL - 1);
    const int grp4 = blockIdx.x >> SH;
    const int wid = threadIdx.x >> 6, lane = threadIdx.x & 63;
    const int grp = grp4 * 4 + wid;          // 16-node group id (wave-uniform)
    const int nslot = lane >> 2, q = lane & 3;
    const int gpos = grp * 16 + nslot;       // perm index
    const int node = perm[gpos];             // NN for padding lanes
    const int nt = gcap[grp];                // uniform trip count, mult of 8, >=8

    const u16* gslb = gs + (size_t)slice * (NN + 1) * 32 + q * 8;  // quarter base
    const u16* ep = esrc + gbase[grp] + nslot;

    float a[8];
#pragma unroll
    for (int j = 0; j < 8; ++j) a[j] = 0.f;

    // ---- prologue: srcs chunks 0,1; self row; rows chunks 0,1; srcs 2,3 ----
    int a0 = (int)ep[0],   a1 = (int)ep[16],  a2 = (int)ep[32],  a3 = (int)ep[48];
    int b0 = (int)ep[64],  b1 = (int)ep[80],  b2 = (int)ep[96],  b3 = (int)ep[112];
    uint4 RS = *(const uint4*)(gslb + (size_t)node * 32);
    uint4 A0 = *(const uint4*)(gslb + (size_t)a0 * 32);
    uint4 A1 = *(const uint4*)(gslb + (size_t)a1 * 32);
    uint4 A2 = *(const uint4*)(gslb + (size_t)a2 * 32);
    uint4 A3 = *(const uint4*)(gslb + (size_t)a3 * 32);
    uint4 B0 = *(const uint4*)(gslb + (size_t)b0 * 32);
    uint4 B1 = *(const uint4*)(gslb + (size_t)b1 * 32);
    uint4 B2 = *(const uint4*)(gslb + (size_t)b2 * 32);
    uint4 B3 = *(const uint4*)(gslb + (size_t)b3 * 32);
    CONSROW(RS);
    if (8 < nt) {   // srcs chunk 2 (slots 8..11)
        a0 = (int)ep[128]; a1 = (int)ep[144]; a2 = (int)ep[160]; a3 = (int)ep[176];
    }
    if (12 < nt) {  // srcs chunk 3 (slots 12..15)
        b0 = (int)ep[192]; b1 = (int)ep[208]; b2 = (int)ep[224]; b3 = (int)ep[240];
    }

    // ---- main loop: 2 chunks (8 rows) per iteration ----
    int c = 0;  // chunk index (4 slots each); nt/4 chunks total, even
    for (;;) {
        CONSROW(A0); CONSROW(A1); CONSROW(A2); CONSROW(A3);        // chunk c
        if ((c + 2) * 4 >= nt) {
            CONSROW(B0); CONSROW(B1); CONSROW(B2); CONSROW(B3);    // chunk c+1
            break;
        }
        A0 = *(const uint4*)(gslb + (size_t)a0 * 32);              // rows chunk c+2
        A1 = *(const uint4*)(gslb + (size_t)a1 * 32);
        A2 = *(const uint4*)(gslb + (size_t)a2 * 32);
        A3 = *(const uint4*)(gslb + (size_t)a3 * 32);
        if ((c + 4) * 4 < nt) {                                    // srcs chunk c+4
            const u16* sp = ep + (size_t)(c + 4) * 64;
            a0 = (int)sp[0]; a1 = (int)sp[16]; a2 = (int)sp[32]; a3 = (int)sp[48];
        }
        CONSROW(B0); CONSROW(B1); CONSROW(B2); CONSROW(B3);        // chunk c+1
        B0 = *(const uint4*)(gslb + (size_t)b0 * 32);              // rows chunk c+3
        B1 = *(const uint4*)(gslb + (size_t)b1 * 32);
        B2 = *(const uint4*)(gslb + (size_t)b2 * 32);
        B3 = *(const uint4*)(gslb + (size_t)b3 * 32);
        if ((c + 5) * 4 < nt) {                                    // srcs chunk c+5
            const u16* sp = ep + (size_t)(c + 5) * 64;
            b0 = (int)sp[0]; b1 = (int)sp[16]; b2 = (int)sp[32]; b3 = (int)sp[48];
        }
        c += 2;
    }

    if (node < NN) {
        const float dv = dinv[node];
        const int f = slice * 32 + q * 8;
        float v[8];
        f32x4 bb0 = *(const f32x4*)(bias + f);
        f32x4 bb1 = *(const f32x4*)(bias + f + 4);
#pragma unroll
        for (int j = 0; j < 4; ++j) v[j] = a[j] * dv + bb0[j];
#pragma unroll
        for (int j = 0; j < 4; ++j) v[j + 4] = a[j + 4] * dv + bb1[j];

        if (FINAL) {
            float* op = outf + (size_t)node * Dc + f;
            *(f32x4*)op = (f32x4){v[0], v[1], v[2], v[3]};
            *(f32x4*)(op + 4) = (f32x4){v[4], v[5], v[6], v[7]};
        } else {
            float* vp = vs + ((size_t)slice * NN + node) * 32 + q * 8;
            *(f32x4*)vp = (f32x4){v[0], v[1], v[2], v[3]};
            *(f32x4*)(vp + 4) = (f32x4){v[4], v[5], v[6], v[7]};
            float p1 = 0.f, p2 = 0.f;
#pragma unroll
            for (int j = 0; j < 8; ++j) {
                p1 += v[j];
                p2 += v[j] * v[j];
            }
            // quad reduction (4 lanes of this node)
            p1 += __shfl_xor(p1, 1, 64); p2 += __shfl_xor(p2, 1, 64);
            p1 += __shfl_xor(p1, 2, 64); p2 += __shfl_xor(p2, 2, 64);
            // part[slice][node]: per-XCD-contiguous -> no cross-XCD false sharing
            if (q == 0)
                *(f32x2*)(part + ((size_t)slice * NN + node) * 2) = (f32x2){p1, p2};
        }
    }
}

// ---------------- LN + SiLU + bf16 hi/lo split (streaming, r9 verbatim) ------
__global__ __launch_bounds__(256) void ln_kernel(const float* __restrict__ vs,
                                                 const float* __restrict__ part,
                                                 const float* __restrict__ gamma,
                                                 const float* __restrict__ beta,
                                                 u16* __restrict__ xhi,
                                                 u16* __restrict__ xlo) {
    const int wid = threadIdx.x >> 6, lane = threadIdx.x & 63;
    const int node = blockIdx.x * 4 + wid;
    const int s = lane >> 3, o = (lane & 7) * 4;

    f32x4 vv = *(const f32x4*)(vs + ((size_t)s * NN + node) * 32 + o);
    f32x2 p = *(const f32x2*)(part + ((size_t)(lane & 7) * NN + node) * 2);
    float s1 = p.x, s2 = p.y;
    s1 += __shfl_xor(s1, 1, 64); s2 += __shfl_xor(s2, 1, 64);
    s1 += __shfl_xor(s1, 2, 64); s2 += __shfl_xor(s2, 2, 64);
    s1 += __shfl_xor(s1, 4, 64); s2 += __shfl_xor(s2, 4, 64);

    const float mu = s1 * (1.f / 256.f);
    const float var = s2 * (1.f / 256.f) - mu * mu;
    const float rstd = rsqrtf(fmaxf(var, 0.f) + 1e-5f);

    const int f = s * 32 + o;
    u16 hh[4], ll[4];
#pragma unroll
    for (int j = 0; j < 4; ++j) {
        float y = (vv[j] - mu) * rstd * gamma[f + j] + beta[f + j];
        y = y / (1.f + __expf(-y));
        split2(y, hh[j], ll[j]);
    }
    uint2 oh, ol;
    oh.x = (u32)hh[0] | ((u32)hh[1] << 16);
    oh.y = (u32)hh[2] | ((u32)hh[3] << 16);
    ol.x = (u32)ll[0] | ((u32)ll[1] << 16);
    ol.y = (u32)ll[2] | ((u32)ll[3] << 16);
    *(uint2*)(xhi + (size_t)node * 256 + f) = oh;
    *(uint2*)(xlo + (size_t)node * 256 + f) = ol;
}

// ---------------- launcher ----------------

extern "C" void kernel_launch(void* const* d_in, const int* in_sizes, int n_in,
                              void* d_out, int out_size, void* d_ws, size_t ws_size,
                              hipStream_t stream) {
    (void)in_sizes; (void)n_in; (void)out_size; (void)ws_size;
    const float* x_in  = (const float*)d_in[0];
    const int*   ei    = (const int*)d_in[1];
    const float* W_in  = (const float*)d_in[2];
    const float* b_in  = (const float*)d_in[3];
    const float* W_mid = (const float*)d_in[4];
    const float* b_mid = (const float*)d_in[5];
    const float* W_out = (const float*)d_in[6];
    const float* b_out = (const float*)d_in[7];
    const float* gamma = (const float*)d_in[8];
    const float* beta  = (const float*)d_in[9];

    char* ws = (char*)d_ws;
    size_t off = 0;
    auto alloc = [&](size_t bytes) -> char* {
        char* p = ws + off;
        off += (bytes + 255) & ~(size_t)255;
        return p;
    };
    float* dinv   = (float*)alloc((size_t)NN * 4);
    int* counts   = (int*)alloc((size_t)NN * 4);
    int* rank     = (int*)alloc((size_t)NE * 4);
    int* bcnt     = (int*)alloc((size_t)NBKB * NBIN * 4);
    int* bbase    = (int*)alloc((size_t)NBKB * NBIN * 4);
    int* perm     = (int*)alloc((size_t)NNP * 4);
    int* posv     = (int*)alloc((size_t)NN * 4);
    int* degp     = (int*)alloc((size_t)NNP * 4);
    int* gcap     = (int*)alloc((size_t)NG16 * 4);
    int* gbase    = (int*)alloc((size_t)NG16 * 4);
    u16* esrc     = (u16*)alloc((size_t)ECAP * 2);
    u16* whi_in   = (u16*)alloc((size_t)DIN * DMID * 2);
    u16* wlo_in   = (u16*)alloc((size_t)DIN * DMID * 2);
    u16* whi_mid  = (u16*)alloc((size_t)NMID * DMID * DMID * 2);
    u16* wlo_mid  = (u16*)alloc((size_t)NMID * DMID * DMID * 2);
    u16* whi_out  = (u16*)alloc((size_t)DMID * DOUT * 2);
    u16* wlo_out  = (u16*)alloc((size_t)DMID * DOUT * 2);
    u16* xhi      = (u16*)alloc((size_t)NN * DMID * 2);
    u16* xlo      = (u16*)alloc((size_t)NN * DMID * 2);
    u16* gs       = (u16*)alloc((size_t)8 * (NN + 1) * 32 * 2);  // sliced g
    float* vs     = (float*)alloc((size_t)NN * DMID * 4);        // pre-LN v, sliced
    float* part   = (float*)alloc((size_t)8 * NN * 2 * 4);       // [slice][node]{2}

    hipMemsetAsync(counts, 0, (size_t)NN * 4, stream);

    const int EB4 = (NE / 4 + 255) / 256;       // 1563
    rank_kernel<<<EB4, 256, 0, stream>>>(ei, counts, rank);
    hist2_kernel<<<NBKB, 256, 0, stream>>>(counts, bcnt);
    bscan_kernel<<<1, 128, 0, stream>>>(bcnt, bbase);
    psort2_kernel<<<NBKB, 256, 0, stream>>>(counts, bbase, perm, posv, degp, dinv);
    ptail_kernel<<<1, 64, 0, stream>>>(perm, degp);
    gcap_kernel<<<(NG16 + 255) / 256, 256, 0, stream>>>(degp, gcap);
    gscan_kernel<<<1, 1024, 0, stream>>>(gcap, gbase);
    efill_kernel<<<(ECAP / 8 + 255) / 256, 256, 0, stream>>>(esrc);
    escat_kernel<<<EB4, 256, 0, stream>>>(ei, rank, posv, gbase, esrc);
    zsent_kernel<<<1, 256, 0, stream>>>(gs);

    wsplit_kernel<<<(DIN * DMID + 255) / 256, 256, 0, stream>>>(W_in, whi_in, wlo_in, DIN, DMID);
    wsplitall_kernel<<<(NMID * DMID * DMID + 255) / 256, 256, 0, stream>>>(W_mid, whi_mid, wlo_mid);
    wsplit_kernel<<<(DMID * DOUT + 255) / 256, 256, 0, stream>>>(W_out, whi_out, wlo_out, DMID, DOUT);
    xsplit_kernel<<<1024, 256, 0, stream>>>(x_in, xhi, xlo);

    const int GB = (NN + 127) / 128;            // 391 (8 waves/block)
    const int AGM = (NG16 / 4) * 8;             // 6256: 8 slices x 782 group-quads
    const int AGF = (NG16 / 4) * 4;             // 3128: 4 slices
    const int LNB = NN / 4;                     // 12500

    // layer 0: 128 -> 256
    gemm_kernel<DIN, DMID><<<GB, 512, 0, stream>>>(xhi, xlo, whi_in, wlo_in, dinv, gs);
    agg_kernel<DMID, false><<<AGM, 256, 0, stream>>>(gs, esrc, gbase, gcap, perm,
                                                     dinv, b_in, vs, part, nullptr);
    ln_kernel<<<LNB, 256, 0, stream>>>(vs, part, gamma, beta, xhi, xlo);
    // 8 mid layers: 256 -> 256
    for (int i = 0; i < NMID; ++i) {
        gemm_kernel<DMID, DMID><<<GB, 512, 0, stream>>>(xhi, xlo,
                                                        whi_mid + (size_t)i * DMID * DMID,
                                                        wlo_mid + (size_t)i * DMID * DMID,
                                                        dinv, gs);
        agg_kernel<DMID, false><<<AGM, 256, 0, stream>>>(gs, esrc, gbase, gcap, perm,
                                                         dinv, b_mid + (size_t)i * DMID,
                                                         vs, part, nullptr);
        ln_kernel<<<LNB, 256, 0, stream>>>(vs, part,
                                           gamma + (size_t)(i + 1) * DMID,
                                           beta + (size_t)(i + 1) * DMID, xhi, xlo);
    }
    // final layer: 256 -> 128, no LN/SiLU; agg writes fp32 out directly
    gemm_kernel<DMID, DOUT><<<GB, 512, 0, stream>>>(xhi, xlo, whi_out, wlo_out, dinv, gs);
    agg_kernel<DOUT, true><<<AGF, 256, 0, stream>>>(gs, esrc, gbase, gcap, perm,
                                                    dinv, b_out, nullptr, nullptr,
                                                    (float*)d_out);
}